// Round 6
// baseline (245.128 us; speedup 1.0000x reference)
//
#include <hip/hip_runtime.h>

// Biaffine: out[b,x,y] = Daug[b,x,:]·U·H[b,y,:] + Daug[b,x,:]·W[:d+1] + H[b,y,:]·W[d+1:]
// B=32, S=512, d=1024.  bf16 MFMA two-stage GEMM, casts fused into the GEMMs:
//   gemm1: T = bf16(D) @ Ut^T + U[d,:]   (A = fp32 D reg-staged; y==0 also linD)
//   gemm2: out[b] = T[b] @ bf16(H[b])^T + linD + linH (B = fp32 H reg-staged)
// R9: double-buffered async operand.  R8 post-mortem: the fp32 reg-prefetch
//   hid fp32 latency but the async bf16 side was still issued+drained inside
//   one K-step (single LDS buffer forces vmcnt to retire it pre-barrier) —
//   a full HBM round-trip exposed per iteration, MfmaUtil stuck at 16%.
//   Now: tile k MFMAs on Sasync[k&1]+Sf32 while async tile k+1 -> Sasync[k&1^1]
//   and fp32 prefetch k+1 -> regs both stay in flight across both barriers and
//   the whole MFMA phase.  Per-tile wait = vmcnt(12): retires the PREVIOUS
//   tile's {async(4)+prefetch(8)} which had a full iteration to land.
//   Uniform counts on the last tile via clamped issue + keep-alive (rule #17);
//   sched_barrier(0) after every asm waitcnt (rule #18).
// R3 swizzle kept: LDS chunk (16B) for (row,q): c=(row>>3)*64+(row&7)*8+(q^(row&7)).

#define D_DIM 1024
#define ROWS 16384   // B*S

typedef float floatx4 __attribute__((ext_vector_type(4)));
typedef __bf16 bf16x8 __attribute__((ext_vector_type(8)));
typedef __bf16 bf16x4 __attribute__((ext_vector_type(4)));

__device__ inline unsigned short f2bf(float f) {
  unsigned int u = __builtin_bit_cast(unsigned int, f);
  u = (u + 0x7FFFu + ((u >> 16) & 1u)) >> 16;   // round-nearest-even
  return (unsigned short)u;
}

__device__ inline void async_load16(const void* g, void* l) {
  __builtin_amdgcn_global_load_lds(
      (const __attribute__((address_space(1))) void*)g,
      (__attribute__((address_space(3))) void*)l, 16, 0, 0);
}

// ---- transpose U (first 1024 rows) to bf16 Ut[n][k] = U[k][n] ---------------
// Block (0,0) additionally stages Wh = W[d+1 : 2d+1] (aligned copy; the raw
// offset is 4B-misaligned).  transU runs first on the stream.
__global__ __launch_bounds__(256) void transU_kernel(
    const float* __restrict__ U, const float* __restrict__ W,
    unsigned short* __restrict__ Ut, float* __restrict__ Wh) {
  if (blockIdx.x == 0 && blockIdx.y == 0) {
    #pragma unroll
    for (int i = 0; i < 4; ++i)
      Wh[threadIdx.x + 256 * i] = W[D_DIM + 1 + threadIdx.x + 256 * i];
  }
  __shared__ float tile[32][33];
  int n0 = blockIdx.x * 32;
  int k0 = blockIdx.y * 32;
  int t = threadIdx.x;
  int tr = t >> 5, tc = t & 31;
  #pragma unroll
  for (int i = 0; i < 32; i += 8)
    tile[tr + i][tc] = U[(size_t)(k0 + tr + i) * D_DIM + n0 + tc];
  __syncthreads();
  #pragma unroll
  for (int i = 0; i < 32; i += 8)
    Ut[(size_t)(n0 + tr + i) * D_DIM + k0 + tc] = f2bf(tile[tc][tr + i]);
}

// ---- pipelined mixed-operand MFMA core: 128x128 tile, BK=64 -----------------
// Tile body: [bar#1] -> issue async k+1 -> Snxt, fp32 prefetch k+1 -> vnxt ->
// [vmcnt(12): retire PREV tile's async+prefetch] -> stage fp32 tile k (lin-FMA
// from LDS W, cvt, swizzled ds_write -> Sf32) -> [lgkmcnt(0), bar#2] ->
// ds_read frags from (Sf32, Scur) + 32 MFMA.  This tile's 12 loads fly
// through the barriers and the MFMA phase.
template <bool F32_IS_A>
__device__ inline void gemm_core_mixed(
    const unsigned short* __restrict__ Ga,  // async bf16 side, tile row 0
    const float* __restrict__ Gf,           // fp32 side, tile row 0
    bool do_lin, const float* WvS,          // lin weights in LDS (len 1024)
    float (&part)[8],
    unsigned short* Sf32, unsigned short* Sa0, unsigned short* Sa1,
    floatx4 (&acc)[4][4]) {
  const int K = D_DIM;
  int tid = threadIdx.x;
  int l = tid & 63, wave = tid >> 6;
  int quad = l >> 4, lrow = l & 15;
  int wm = wave >> 1, wn = wave & 1;

  int srow = 8 * wave + (l >> 3);              // +32*j per issue
  int sq = (l & 7) ^ (l >> 3);
  const unsigned short* gasync = Ga + (size_t)srow * K + sq * 8;

  int rl = lrow & 7, gofs = lrow >> 3;
  int baseA = wm * 512 + gofs * 64 + rl * 8;
  int baseB = wn * 512 + gofs * 64 + rl * 8;

  int qi = tid & 15, frow = tid >> 4;          // fp32 side: quad qi of rows 16i+frow
  const float* gf = Gf + (size_t)frow * K + qi * 4;
  int half = qi & 1, q = qi >> 1;
  int cofs[8];
  #pragma unroll
  for (int i = 0; i < 8; ++i) {
    int row = 16 * i + frow;
    cofs[i] = ((row >> 3) * 64 + (row & 7) * 8 + (q ^ (row & 7))) * 8 + half * 4;
  }

  float4 vA[8], vB[8];
  // prologue: tile 0 async -> Sa0, tile 0 fp32 -> vA  (12 outstanding)
  #pragma unroll
  for (int j = 0; j < 4; ++j)
    async_load16(gasync + (size_t)(32 * j) * K, Sa0 + (j * 256 + tid) * 8);
  __builtin_amdgcn_sched_barrier(0);
  #pragma unroll
  for (int i = 0; i < 8; ++i)
    vA[i] = *(const float4*)(gf + (size_t)(16 * i) * K);
  __builtin_amdgcn_sched_barrier(0);

#define TILE_BODY(K0, KN, VCUR, VNXT, SCUR, SNXT)                              \
  {                                                                            \
    asm volatile("" ::: "memory");                                             \
    __builtin_amdgcn_s_barrier();               /* readers of SNXT/Sf32 done */\
    asm volatile("" ::: "memory");                                             \
    _Pragma("unroll")                                                          \
    for (int j = 0; j < 4; ++j)                                                \
      async_load16(gasync + (size_t)(32 * j) * K + (KN),                       \
                   (SNXT) + (j * 256 + tid) * 8);                              \
    __builtin_amdgcn_sched_barrier(0);                                         \
    _Pragma("unroll")                                                          \
    for (int i = 0; i < 8; ++i)                                                \
      (VNXT)[i] = *(const float4*)(gf + (size_t)(16 * i) * K + (KN));          \
    __builtin_amdgcn_sched_barrier(0);                                         \
    /* retire PREV tile's async(4)+prefetch(8); keep this tile's 12 flying */  \
    asm volatile("s_waitcnt vmcnt(12)" ::: "memory");                          \
    __builtin_amdgcn_sched_barrier(0);                                         \
    if (do_lin) {                                                              \
      float4 wq = *(const float4*)&WvS[(K0) + qi * 4];                         \
      _Pragma("unroll")                                                        \
      for (int i = 0; i < 8; ++i)                                              \
        part[i] += (VCUR)[i].x * wq.x + (VCUR)[i].y * wq.y +                   \
                   (VCUR)[i].z * wq.z + (VCUR)[i].w * wq.w;                    \
    }                                                                          \
    _Pragma("unroll")                                                          \
    for (int i = 0; i < 8; ++i) {                                              \
      bf16x4 o = { (__bf16)(VCUR)[i].x, (__bf16)(VCUR)[i].y,                   \
                   (__bf16)(VCUR)[i].z, (__bf16)(VCUR)[i].w };                 \
      *(bf16x4*)(Sf32 + cofs[i]) = o;           /* ds_write_b64, no conflict */\
    }                                                                          \
    asm volatile("s_waitcnt lgkmcnt(0)" ::: "memory");                         \
    __builtin_amdgcn_sched_barrier(0);                                         \
    __builtin_amdgcn_s_barrier();               /* tile K0 published */        \
    asm volatile("" ::: "memory");                                             \
    const unsigned short* Ap = F32_IS_A ? Sf32 : (SCUR);                       \
    const unsigned short* Bp = F32_IS_A ? (SCUR) : Sf32;                       \
    _Pragma("unroll")                                                          \
    for (int s = 0; s < 2; ++s) {                                              \
      int xq = (s * 4 + quad) ^ rl;                                            \
      bf16x8 a[4], b[4];                                                       \
      _Pragma("unroll")                                                        \
      for (int mt = 0; mt < 4; ++mt)                                           \
        a[mt] = *(const bf16x8*)(Ap + (baseA + mt * 128 + xq) * 8);            \
      _Pragma("unroll")                                                        \
      for (int nt = 0; nt < 4; ++nt)                                           \
        b[nt] = *(const bf16x8*)(Bp + (baseB + nt * 128 + xq) * 8);            \
      _Pragma("unroll")                                                        \
      for (int mt = 0; mt < 4; ++mt)                                           \
        _Pragma("unroll")                                                      \
        for (int nt = 0; nt < 4; ++nt)                                         \
          acc[mt][nt] = __builtin_amdgcn_mfma_f32_16x16x32_bf16(               \
              a[mt], b[nt], acc[mt][nt], 0, 0, 0);                             \
    }                                                                          \
  }

  for (int di = 0; di < 8; ++di) {             // 2 tiles per trip, ping-pong
    int k0 = di * 128;
    int knb = (k0 + 128 < K) ? (k0 + 128) : (K - 64);   // last: clamped
    TILE_BODY(k0,      k0 + 64, vA, vB, Sa0, Sa1);
    TILE_BODY(k0 + 64, knb,     vB, vA, Sa1, Sa0);
  }
#undef TILE_BODY

  // keep final clamped prefetch alive: DCE would change vmcnt accounting.
  #pragma unroll
  for (int i = 0; i < 8; ++i)
    asm volatile("" :: "v"(vA[i].x), "v"(vA[i].y), "v"(vA[i].z), "v"(vA[i].w));
}

// ---- GEMM1: T[m][n] = sum_k bf16(D[m][k]) * Ut[n][k] + Ubias[n], bf16 out ---
// A = fp32 D (reg-staged cast); B = Ut (async).  y==0 blocks compute linD.
// grid (128, 8): id%8 = mtile%8 -> 8 n-blocks sharing an A row-tile per XCD.
__global__ __launch_bounds__(256) void gemm1_kernel(
    const float* __restrict__ Df,            // [16384,1024] fp32
    const unsigned short* __restrict__ Ut,   // [1024,1024]  bf16 bits
    const float* __restrict__ Ubias,         // fp32, len 1024 (row d of U)
    const float* __restrict__ W,             // [2049] fp32
    unsigned short* __restrict__ T,
    float* __restrict__ linD) {
  __shared__ __align__(16) unsigned short Sf32[128 * 64];
  __shared__ __align__(16) unsigned short Sa0[128 * 64];
  __shared__ __align__(16) unsigned short Sa1[128 * 64];
  __shared__ float WvS[1024];
  int m0 = blockIdx.x * 128, n0 = blockIdx.y * 128;
  int tid = threadIdx.x;
  int lane = tid & 63, wave = tid >> 6;
  int quad = lane >> 4, lrow = lane & 15;
  int wm = wave >> 1, wn = wave & 1;
  bool do_lin = (blockIdx.y == 0);

  ((float4*)WvS)[tid] = ((const float4*)W)[tid];   // W[0:1024] -> LDS
  __syncthreads();

  float part[8] = {};
  floatx4 acc[4][4] = {};
  gemm_core_mixed<true>(Ut + (size_t)n0 * D_DIM, Df + (size_t)m0 * D_DIM,
                        do_lin, WvS, part, Sf32, Sa0, Sa1, acc);

  // C/D layout: col = lane&15, row = quad*4 + reg  [m89-verified]
  #pragma unroll
  for (int mt = 0; mt < 4; ++mt)
    #pragma unroll
    for (int nt = 0; nt < 4; ++nt) {
      int row = m0 + wm * 64 + mt * 16 + quad * 4;
      int col = n0 + wn * 64 + nt * 16 + lrow;
      float bias = Ubias[col];
      #pragma unroll
      for (int rr = 0; rr < 4; ++rr)
        T[(size_t)(row + rr) * D_DIM + col] = f2bf(acc[mt][nt][rr] + bias);
    }

  if (do_lin) {                               // reduce D·W partials -> linD
    __syncthreads();                          // full drain: LDS reads + stray DMA done
    float* red = (float*)Sf32;                // 128 rows x 16 = 8KB scratch
    #pragma unroll
    for (int i = 0; i < 8; ++i)
      red[(16 * i + (tid >> 4)) * 16 + (tid & 15)] = part[i];
    __syncthreads();
    if (tid < 128) {
      float s = 0.f;
      #pragma unroll
      for (int j = 0; j < 16; ++j) s += red[tid * 16 + j];
      linD[m0 + tid] = s + W[D_DIM];          // ones-column bias
    }
  }
}

// ---- GEMM2: out[b,x,y] = sum_k T[b,x,k]*bf16(H[b,y,k]) + linD + linH --------
// A = T (async); B = fp32 H (reg-staged cast).  Every block computes linH for
// its own 128 cols during staging (kept in LDS, no global round-trip).
// grid (32, 16): id%8 = b%8 -> batch's 16 blocks on one XCD (T[b]+H[b] ~ L2).
__global__ __launch_bounds__(256) void gemm2_kernel(
    const unsigned short* __restrict__ Tg,   // [32*512,1024] bf16 bits
    const float* __restrict__ Hf,            // [32*512,1024] fp32
    const float* __restrict__ Wh,            // aligned W[d+1:], len 1024
    const float* __restrict__ linD,
    float* __restrict__ out) {               // [32,512,512]
  __shared__ __align__(16) unsigned short Sf32[128 * 64];
  __shared__ __align__(16) unsigned short Sa0[128 * 64];
  __shared__ __align__(16) unsigned short Sa1[128 * 64];
  __shared__ float WvS[1024];
  __shared__ float linh_s[128];
  int b = blockIdx.x;
  int t = blockIdx.y;
  int m0 = (t >> 2) * 128, n0 = (t & 3) * 128;
  int tid = threadIdx.x;
  int lane = tid & 63, wave = tid >> 6;
  int quad = lane >> 4, lrow = lane & 15;
  int wm = wave >> 1, wn = wave & 1;

  ((float4*)WvS)[tid] = ((const float4*)Wh)[tid];  // Wh[0:1024] -> LDS
  __syncthreads();

  float part[8] = {};
  floatx4 acc[4][4] = {};
  gemm_core_mixed<false>(Tg + ((size_t)b * 512 + m0) * D_DIM,
                         Hf + ((size_t)b * 512 + n0) * D_DIM,
                         true, WvS, part, Sf32, Sa0, Sa1, acc);

  // reduce H·Wh partials -> linh_s (cols n0..n0+127 of this block)
  __syncthreads();                            // full drain before LDS reuse
  float* red = (float*)Sa0;
  #pragma unroll
  for (int i = 0; i < 8; ++i)
    red[(16 * i + (tid >> 4)) * 16 + (tid & 15)] = part[i];
  __syncthreads();
  if (tid < 128) {
    float s = 0.f;
    #pragma unroll
    for (int j = 0; j < 16; ++j) s += red[tid * 16 + j];
    linh_s[tid] = s;
  }
  __syncthreads();

  #pragma unroll
  for (int mt = 0; mt < 4; ++mt)
    #pragma unroll
    for (int nt = 0; nt < 4; ++nt) {
      int row = m0 + wm * 64 + mt * 16 + quad * 4;
      int col = n0 + wn * 64 + nt * 16 + lrow;
      float lh = linh_s[wn * 64 + nt * 16 + lrow];
      #pragma unroll
      for (int rr = 0; rr < 4; ++rr) {
        float v = acc[mt][nt][rr] + linD[b * 512 + row + rr] + lh;
        out[((size_t)b * 512 + row + rr) * 512 + col] = v;
      }
    }
}

extern "C" void kernel_launch(void* const* d_in, const int* in_sizes, int n_in,
                              void* d_out, int out_size, void* d_ws, size_t ws_size,
                              hipStream_t stream) {
  const float* D = (const float*)d_in[0];
  const float* H = (const float*)d_in[1];
  const float* U = (const float*)d_in[2];   // [1025,1024]
  const float* W = (const float*)d_in[3];   // [2049]
  float* out = (float*)d_out;

  char* ws = (char*)d_ws;
  unsigned short* Tbf = (unsigned short*)ws; ws += (size_t)ROWS * D_DIM * 2;   // 32 MB
  unsigned short* Ut  = (unsigned short*)ws; ws += (size_t)D_DIM * D_DIM * 2;  //  2 MB
  float* linD = (float*)ws;                  ws += (size_t)ROWS * 4;
  float* Wh   = (float*)ws;                  ws += (size_t)D_DIM * 4;          // aligned W[d+1:]

  transU_kernel<<<dim3(32, 32), 256, 0, stream>>>(U, W, Ut, Wh);
  gemm1_kernel<<<dim3(128, 8), 256, 0, stream>>>(D, Ut, U + (size_t)D_DIM * D_DIM, W, Tbf, linD);
  gemm2_kernel<<<dim3(32, 16), 256, 0, stream>>>(Tbf, H, Wh, linD, out);
}

// Round 7
// 234.119 us; speedup vs baseline: 1.0470x; 1.0470x over previous
//
#include <hip/hip_runtime.h>

// Biaffine: out[b,x,y] = Daug[b,x,:]·U·H[b,y,:] + Daug[b,x,:]·W[:d+1] + H[b,y,:]·W[d+1:]
// B=32, S=512, d=1024.  bf16 MFMA two-stage GEMM:
//   T = D @ U[0:d,:] + U[d,:]            (16384 x 1024 x 1024, bf16 out)
//   out[b] = T[b] @ H[b]^T + linD + linH (32 x 512x512x1024, fp32 out)
// R10: REVERT to the round-0 baseline structure (best measured: 220.9 µs).
//   R4-R9 post-mortem: every cast rewrite (R4-R6) and every cast-into-GEMM
//   fusion (R7-R9) lost to the baseline's all-bf16 async-both-sides core
//   (baseline gemm1/gemm2 each <50 µs; fused mixed cores 70-80 µs).
//   Single change this round: gemm2 tile 128x128 -> 128x64 (grid 32x16 ->
//   32x32 = 1024 blocks, 4 blocks/CU instead of 2).  Mechanism: gemm2 was
//   the only kernel at 2 blocks/CU; barrier drains had no cross-block
//   overlap.  Core templated on wave geometry; gemm1 instantiates the
//   identical baseline config.
// R3 swizzle kept: LDS chunk (16B) for (row,q): c=(row>>3)*64+(row&7)*8+(q^(row&7)).

#define D_DIM 1024
#define ROWS 16384   // B*S

typedef float floatx4 __attribute__((ext_vector_type(4)));
typedef __bf16 bf16x8 __attribute__((ext_vector_type(8)));

__device__ inline unsigned short f2bf(float f) {
  unsigned int u = __builtin_bit_cast(unsigned int, f);
  u = (u + 0x7FFFu + ((u >> 16) & 1u)) >> 16;   // round-nearest-even
  return (unsigned short)u;
}

__device__ inline void async_load16(const void* g, void* l) {
  __builtin_amdgcn_global_load_lds(
      (const __attribute__((address_space(1))) void*)g,
      (__attribute__((address_space(3))) void*)l, 16, 0, 0);
}

// ---- cast D/H to bf16 + fused linear-term dot products ----------------------
// (round-0 version, verbatim — best measured variant of this pass)
__global__ __launch_bounds__(256) void cast_rows_kernel(
    const float* __restrict__ D, const float* __restrict__ H,
    const float* __restrict__ W,
    unsigned short* __restrict__ Dbf, unsigned short* __restrict__ Hbf,
    float* __restrict__ linD, float* __restrict__ linH) {
  int rowid = blockIdx.x;
  bool isH = rowid >= ROWS;
  int r = isH ? rowid - ROWS : rowid;
  const float* src = (isH ? H : D) + (size_t)r * D_DIM;
  unsigned short* dst = (isH ? Hbf : Dbf) + (size_t)r * D_DIM;
  const float* w = W + (isH ? (D_DIM + 1) : 0);
  int t = threadIdx.x;                 // 256 threads, 4 elems each
  float4 v = ((const float4*)src)[t];
  float s = v.x * w[4*t] + v.y * w[4*t+1] + v.z * w[4*t+2] + v.w * w[4*t+3];
  ushort4 o;
  o.x = f2bf(v.x); o.y = f2bf(v.y); o.z = f2bf(v.z); o.w = f2bf(v.w);
  ((ushort4*)dst)[t] = o;
  #pragma unroll
  for (int off = 32; off > 0; off >>= 1) s += __shfl_down(s, off, 64);
  __shared__ float red[4];
  int wave = t >> 6;
  if ((t & 63) == 0) red[wave] = s;
  __syncthreads();
  if (t == 0) {
    float tot = red[0] + red[1] + red[2] + red[3];
    if (!isH) tot += W[D_DIM];         // ones-column bias for Daug side
    (isH ? linH : linD)[r] = tot;
  }
}

// ---- transpose U (first 1024 rows) to bf16 Ut[n][k] = U[k][n] ---------------
__global__ __launch_bounds__(256) void transU_kernel(
    const float* __restrict__ U, unsigned short* __restrict__ Ut) {
  __shared__ float tile[32][33];
  int n0 = blockIdx.x * 32;
  int k0 = blockIdx.y * 32;
  int t = threadIdx.x;
  int tr = t >> 5, tc = t & 31;
  #pragma unroll
  for (int i = 0; i < 32; i += 8)
    tile[tr + i][tc] = U[(size_t)(k0 + tr + i) * D_DIM + n0 + tc];
  __syncthreads();
  #pragma unroll
  for (int i = 0; i < 32; i += 8)
    Ut[(size_t)(n0 + tr + i) * D_DIM + k0 + tc] = f2bf(tile[tc][tr + i]);
}

// ---- swizzled MFMA K-loop core, templated tile geometry, BK=64 --------------
// A-tile is always 128 rows; B-tile is BROWS (128 or 64).  MWAVES x NWAVES
// wave grid; each wave owns (MT*16) x (NT*16) output.
// LDS chunk (16B) for (row,q): c = (row>>3)*64 + (row&7)*8 + (q ^ (row&7)).
// Staging instr j (wave w): group g=j*4+w, lane l -> row 8g+(l>>3),
// q=(l&7)^(l>>3): 8 contiguous 128B global lines, LDS dest = base + lane*16.
// Frag read: 8-round minimum, no conflicts.
template <int MWAVES, int NWAVES, int MT, int NT, int BROWS>
__device__ inline void gemm_core_swz(
    const unsigned short* __restrict__ A, const unsigned short* __restrict__ Bt,
    int m0, int n0, unsigned short* As, unsigned short* Bs,
    floatx4 (&acc)[MT][NT]) {
  const int K = D_DIM;
  int tid = threadIdx.x;
  int l = tid & 63, wave = tid >> 6;
  int quad = l >> 4, lrow = l & 15;
  int wm = (NWAVES == 2) ? (wave >> 1) : wave;
  int wn = (NWAVES == 2) ? (wave & 1) : 0;

  int srow = 8 * wave + (l >> 3);              // +32*j per issue
  int sq = (l & 7) ^ (l >> 3);
  const unsigned short* gA = A + (size_t)(m0 + srow) * K + sq * 8;
  const unsigned short* gB = Bt + (size_t)(n0 + srow) * K + sq * 8;

  int rl = lrow & 7, gofs = lrow >> 3;
  int baseA = wm * (MT * 128) + gofs * 64 + rl * 8;
  int baseB = wn * (NT * 128) + gofs * 64 + rl * 8;

  for (int k0 = 0; k0 < K; k0 += 64) {
    __syncthreads();
    #pragma unroll
    for (int j = 0; j < 4; ++j)                // A: 128 rows
      async_load16(gA + (size_t)(32 * j) * K + k0, As + (j * 256 + tid) * 8);
    #pragma unroll
    for (int j = 0; j < BROWS / 32; ++j)       // B: BROWS rows
      async_load16(gB + (size_t)(32 * j) * K + k0, Bs + (j * 256 + tid) * 8);
    __syncthreads();
    #pragma unroll
    for (int s = 0; s < 2; ++s) {
      int xq = (s * 4 + quad) ^ rl;
      bf16x8 a[MT], b[NT];
      #pragma unroll
      for (int mt = 0; mt < MT; ++mt)
        a[mt] = *(const bf16x8*)(As + (baseA + mt * 128 + xq) * 8);
      #pragma unroll
      for (int nt = 0; nt < NT; ++nt)
        b[nt] = *(const bf16x8*)(Bs + (baseB + nt * 128 + xq) * 8);
      #pragma unroll
      for (int mt = 0; mt < MT; ++mt)
        #pragma unroll
        for (int nt = 0; nt < NT; ++nt)
          acc[mt][nt] = __builtin_amdgcn_mfma_f32_16x16x32_bf16(
              a[mt], b[nt], acc[mt][nt], 0, 0, 0);
    }
  }
}

// ---- GEMM1: T[m][n] = sum_k Dbf[m][k] * Ut[n][k] + Ubias[n], bf16 out -------
// 128x128 tile (baseline config).  grid (128, 8): id%8 = mtile%8 -> the 8
// n-blocks sharing an A row-tile land on one XCD.
__global__ __launch_bounds__(256) void gemm1_kernel(
    const unsigned short* __restrict__ A,    // [16384,1024] bf16 bits
    const unsigned short* __restrict__ Bt,   // [1024,1024]  bf16 bits
    const float* __restrict__ Ubias,         // fp32, len 1024
    unsigned short* __restrict__ T) {
  __shared__ __align__(16) unsigned short As[128 * 64];
  __shared__ __align__(16) unsigned short Bs[128 * 64];
  int m0 = blockIdx.x * 128, n0 = blockIdx.y * 128;
  int tid = threadIdx.x;
  int lane = tid & 63, wave = tid >> 6;
  int quad = lane >> 4, lrow = lane & 15;
  int wm = wave >> 1, wn = wave & 1;

  floatx4 acc[4][4] = {};
  gemm_core_swz<2, 2, 4, 4, 128>(A, Bt, m0, n0, As, Bs, acc);

  // C/D layout: col = lane&15, row = quad*4 + reg  [m89-verified]
  #pragma unroll
  for (int mt = 0; mt < 4; ++mt)
    #pragma unroll
    for (int nt = 0; nt < 4; ++nt) {
      int row = m0 + wm * 64 + mt * 16 + quad * 4;
      int col = n0 + wn * 64 + nt * 16 + lrow;
      float bias = Ubias[col];
      #pragma unroll
      for (int rr = 0; rr < 4; ++rr)
        T[(size_t)(row + rr) * D_DIM + col] = f2bf(acc[mt][nt][rr] + bias);
    }
}

// ---- GEMM2: out[b,x,y] = sum_k T[b,x,k]*Hbf[b,y,k] + linD[b,x] + linH[b,y] --
// R10: 128x64 tile, grid (32, 32) = 1024 blocks -> 4 blocks/CU (was 2).
// id%8 = b%8 -> each batch's 32 blocks on one XCD; T[b]+H[b] = 2 MB ~ L2.
// 4 waves each own 32x64 (acc[2][4]); B-tile 64 rows -> 2 async issues.
__global__ __launch_bounds__(256) void gemm2_kernel(
    const unsigned short* __restrict__ Tg,   // [32*512,1024]
    const unsigned short* __restrict__ Hbf,  // [32*512,1024]
    const float* __restrict__ linD, const float* __restrict__ linH,
    float* __restrict__ out) {               // [32,512,512]
  __shared__ __align__(16) unsigned short As[128 * 64];
  __shared__ __align__(16) unsigned short Bs[64 * 64];
  int b = blockIdx.x;
  int t = blockIdx.y;
  int m0 = (t >> 3) * 128, n0 = (t & 7) * 64;
  const unsigned short* A = Tg + (size_t)b * 512 * D_DIM;
  const unsigned short* Bt = Hbf + (size_t)b * 512 * D_DIM;
  int tid = threadIdx.x;
  int lane = tid & 63, wave = tid >> 6;
  int quad = lane >> 4, lrow = lane & 15;
  int wm = wave;                              // NWAVES=1: wave owns rows wm*32..

  floatx4 acc[2][4] = {};
  gemm_core_swz<4, 1, 2, 4, 64>(A, Bt, m0, n0, As, Bs, acc);

  #pragma unroll
  for (int mt = 0; mt < 2; ++mt)
    #pragma unroll
    for (int nt = 0; nt < 4; ++nt) {
      int row = m0 + wm * 32 + mt * 16 + quad * 4;
      int col = n0 + nt * 16 + lrow;
      float lh = linH[b * 512 + col];
      #pragma unroll
      for (int rr = 0; rr < 4; ++rr) {
        float v = acc[mt][nt][rr] + linD[b * 512 + row + rr] + lh;
        out[((size_t)b * 512 + row + rr) * 512 + col] = v;
      }
    }
}

extern "C" void kernel_launch(void* const* d_in, const int* in_sizes, int n_in,
                              void* d_out, int out_size, void* d_ws, size_t ws_size,
                              hipStream_t stream) {
  const float* D = (const float*)d_in[0];
  const float* H = (const float*)d_in[1];
  const float* U = (const float*)d_in[2];   // [1025,1024]
  const float* W = (const float*)d_in[3];   // [2049]
  float* out = (float*)d_out;

  char* ws = (char*)d_ws;
  unsigned short* Dbf = (unsigned short*)ws; ws += (size_t)ROWS * D_DIM * 2;   // 32 MB
  unsigned short* Hbf = (unsigned short*)ws; ws += (size_t)ROWS * D_DIM * 2;   // 32 MB
  unsigned short* Tbf = (unsigned short*)ws; ws += (size_t)ROWS * D_DIM * 2;   // 32 MB
  unsigned short* Ut  = (unsigned short*)ws; ws += (size_t)D_DIM * D_DIM * 2;  //  2 MB
  float* linD = (float*)ws;                  ws += (size_t)ROWS * 4;
  float* linH = (float*)ws;                  ws += (size_t)ROWS * 4;

  cast_rows_kernel<<<dim3(2 * ROWS), 256, 0, stream>>>(D, H, W, Dbf, Hbf, linD, linH);
  transU_kernel<<<dim3(32, 32), 256, 0, stream>>>(U, Ut);
  gemm1_kernel<<<dim3(128, 8), 256, 0, stream>>>(Dbf, Ut, U + (size_t)D_DIM * D_DIM, Tbf);
  gemm2_kernel<<<dim3(32, 32), 256, 0, stream>>>(Tbf, Hbf, linD, linH, out);
}

// Round 8
// 224.343 us; speedup vs baseline: 1.0927x; 1.0436x over previous
//
#include <hip/hip_runtime.h>

// Biaffine: out[b,x,y] = Daug[b,x,:]·U·H[b,y,:] + Daug[b,x,:]·W[:d+1] + H[b,y,:]·W[d+1:]
// B=32, S=512, d=1024.  bf16 MFMA two-stage GEMM:
//   T = D @ U[0:d,:] + U[d,:]            (16384 x 1024 x 1024, bf16 out)
//   out[b] = T[b] @ H[b]^T + linD + linH (32 x 512x512x1024, fp32 out)
// R11: consolidation round.
//   - gemm2 REVERTED to R0's 128x128 tile (R10's 128x64 cost ~13 µs: 1.5x
//     staging traffic beat the occupancy gain).
//   - transU folded into the cast launch (blocks >= 2*ROWS take the transpose
//     path) -> one fewer dispatch per iteration.  Dispatch sum (~150 µs) is
//     ~70 µs below wall (221 µs); this probes the launch-overhead hypothesis.
//   - `out` written with non-temporal stores (33.5 MB, never re-read) to keep
//     the LLC for D/H/T/Hbf reads (cast showed ~50% L3 read-hit).
// R3 swizzle kept: LDS chunk (16B) for (row,q): c=(row>>3)*64+(row&7)*8+(q^(row&7)).

#define D_DIM 1024
#define ROWS 16384   // B*S

typedef float floatx4 __attribute__((ext_vector_type(4)));
typedef __bf16 bf16x8 __attribute__((ext_vector_type(8)));

__device__ inline unsigned short f2bf(float f) {
  unsigned int u = __builtin_bit_cast(unsigned int, f);
  u = (u + 0x7FFFu + ((u >> 16) & 1u)) >> 16;   // round-nearest-even
  return (unsigned short)u;
}

__device__ inline void async_load16(const void* g, void* l) {
  __builtin_amdgcn_global_load_lds(
      (const __attribute__((address_space(1))) void*)g,
      (__attribute__((address_space(3))) void*)l, 16, 0, 0);
}

// ---- cast D/H to bf16 + linear terms, AND transpose U (merged launch) -------
// blocks [0, 2*ROWS): R0 cast path verbatim (one row per block, 256 threads,
//   4 elems/thread, shuffle+LDS reduce for the W dot product).
// blocks [2*ROWS, 2*ROWS+1024): R0 transU path (32x32 fp32->bf16 transpose
//   tiles of U; tb%32 = n-tile, tb/32 = k-tile).
__global__ __launch_bounds__(256) void cast_transU_kernel(
    const float* __restrict__ D, const float* __restrict__ H,
    const float* __restrict__ U, const float* __restrict__ W,
    unsigned short* __restrict__ Dbf, unsigned short* __restrict__ Hbf,
    unsigned short* __restrict__ Ut,
    float* __restrict__ linD, float* __restrict__ linH) {
  __shared__ float tile[32][33];               // transU tile; cast uses [0][0..3]
  int bid = blockIdx.x;
  int t = threadIdx.x;

  if (bid < 2 * ROWS) {                        // ---- cast path (R0 verbatim)
    bool isH = bid >= ROWS;
    int r = isH ? bid - ROWS : bid;
    const float* src = (isH ? H : D) + (size_t)r * D_DIM;
    unsigned short* dst = (isH ? Hbf : Dbf) + (size_t)r * D_DIM;
    const float* w = W + (isH ? (D_DIM + 1) : 0);
    float4 v = ((const float4*)src)[t];
    float s = v.x * w[4*t] + v.y * w[4*t+1] + v.z * w[4*t+2] + v.w * w[4*t+3];
    ushort4 o;
    o.x = f2bf(v.x); o.y = f2bf(v.y); o.z = f2bf(v.z); o.w = f2bf(v.w);
    ((ushort4*)dst)[t] = o;
    #pragma unroll
    for (int off = 32; off > 0; off >>= 1) s += __shfl_down(s, off, 64);
    float* red = &tile[0][0];
    int wave = t >> 6;
    if ((t & 63) == 0) red[wave] = s;
    __syncthreads();
    if (t == 0) {
      float tot = red[0] + red[1] + red[2] + red[3];
      if (!isH) tot += W[D_DIM];               // ones-column bias for Daug side
      (isH ? linH : linD)[r] = tot;
    }
  } else {                                     // ---- transU path (R0 verbatim)
    int tb = bid - 2 * ROWS;                   // 0..1023
    int n0 = (tb & 31) * 32;
    int k0 = (tb >> 5) * 32;
    int tr = t >> 5, tc = t & 31;
    #pragma unroll
    for (int i = 0; i < 32; i += 8)
      tile[tr + i][tc] = U[(size_t)(k0 + tr + i) * D_DIM + n0 + tc];
    __syncthreads();
    #pragma unroll
    for (int i = 0; i < 32; i += 8)
      Ut[(size_t)(n0 + tr + i) * D_DIM + k0 + tc] = f2bf(tile[tc][tr + i]);
  }
}

// ---- swizzled MFMA K-loop core, templated tile geometry, BK=64 --------------
// A-tile is always 128 rows; B-tile is BROWS.  MWAVES x NWAVES wave grid.
// LDS chunk (16B) for (row,q): c = (row>>3)*64 + (row&7)*8 + (q ^ (row&7)).
// Staging instr j (wave w): group g=j*4+w, lane l -> row 8g+(l>>3),
// q=(l&7)^(l>>3): 8 contiguous 128B global lines, LDS dest = base + lane*16.
// Frag read: 8-round minimum, no conflicts.
template <int MWAVES, int NWAVES, int MT, int NT, int BROWS>
__device__ inline void gemm_core_swz(
    const unsigned short* __restrict__ A, const unsigned short* __restrict__ Bt,
    int m0, int n0, unsigned short* As, unsigned short* Bs,
    floatx4 (&acc)[MT][NT]) {
  const int K = D_DIM;
  int tid = threadIdx.x;
  int l = tid & 63, wave = tid >> 6;
  int quad = l >> 4, lrow = l & 15;
  int wm = (NWAVES == 2) ? (wave >> 1) : wave;
  int wn = (NWAVES == 2) ? (wave & 1) : 0;

  int srow = 8 * wave + (l >> 3);              // +32*j per issue
  int sq = (l & 7) ^ (l >> 3);
  const unsigned short* gA = A + (size_t)(m0 + srow) * K + sq * 8;
  const unsigned short* gB = Bt + (size_t)(n0 + srow) * K + sq * 8;

  int rl = lrow & 7, gofs = lrow >> 3;
  int baseA = wm * (MT * 128) + gofs * 64 + rl * 8;
  int baseB = wn * (NT * 128) + gofs * 64 + rl * 8;

  for (int k0 = 0; k0 < K; k0 += 64) {
    __syncthreads();
    #pragma unroll
    for (int j = 0; j < 4; ++j)                // A: 128 rows
      async_load16(gA + (size_t)(32 * j) * K + k0, As + (j * 256 + tid) * 8);
    #pragma unroll
    for (int j = 0; j < BROWS / 32; ++j)       // B: BROWS rows
      async_load16(gB + (size_t)(32 * j) * K + k0, Bs + (j * 256 + tid) * 8);
    __syncthreads();
    #pragma unroll
    for (int s = 0; s < 2; ++s) {
      int xq = (s * 4 + quad) ^ rl;
      bf16x8 a[MT], b[NT];
      #pragma unroll
      for (int mt = 0; mt < MT; ++mt)
        a[mt] = *(const bf16x8*)(As + (baseA + mt * 128 + xq) * 8);
      #pragma unroll
      for (int nt = 0; nt < NT; ++nt)
        b[nt] = *(const bf16x8*)(Bs + (baseB + nt * 128 + xq) * 8);
      #pragma unroll
      for (int mt = 0; mt < MT; ++mt)
        #pragma unroll
        for (int nt = 0; nt < NT; ++nt)
          acc[mt][nt] = __builtin_amdgcn_mfma_f32_16x16x32_bf16(
              a[mt], b[nt], acc[mt][nt], 0, 0, 0);
    }
  }
}

// ---- GEMM1: T[m][n] = sum_k Dbf[m][k] * Ut[n][k] + Ubias[n], bf16 out -------
// 128x128 tile (baseline config).  grid (128, 8): id%8 = mtile%8 -> the 8
// n-blocks sharing an A row-tile land on one XCD.
__global__ __launch_bounds__(256) void gemm1_kernel(
    const unsigned short* __restrict__ A,    // [16384,1024] bf16 bits
    const unsigned short* __restrict__ Bt,   // [1024,1024]  bf16 bits
    const float* __restrict__ Ubias,         // fp32, len 1024
    unsigned short* __restrict__ T) {
  __shared__ __align__(16) unsigned short As[128 * 64];
  __shared__ __align__(16) unsigned short Bs[128 * 64];
  int m0 = blockIdx.x * 128, n0 = blockIdx.y * 128;
  int tid = threadIdx.x;
  int lane = tid & 63, wave = tid >> 6;
  int quad = lane >> 4, lrow = lane & 15;
  int wm = wave >> 1, wn = wave & 1;

  floatx4 acc[4][4] = {};
  gemm_core_swz<2, 2, 4, 4, 128>(A, Bt, m0, n0, As, Bs, acc);

  // C/D layout: col = lane&15, row = quad*4 + reg  [m89-verified]
  #pragma unroll
  for (int mt = 0; mt < 4; ++mt)
    #pragma unroll
    for (int nt = 0; nt < 4; ++nt) {
      int row = m0 + wm * 64 + mt * 16 + quad * 4;
      int col = n0 + wn * 64 + nt * 16 + lrow;
      float bias = Ubias[col];
      #pragma unroll
      for (int rr = 0; rr < 4; ++rr)
        T[(size_t)(row + rr) * D_DIM + col] = f2bf(acc[mt][nt][rr] + bias);
    }
}

// ---- GEMM2: out[b,x,y] = sum_k T[b,x,k]*Hbf[b,y,k] + linD[b,x] + linH[b,y] --
// R0 config restored: 128x128 tile, grid (32, 16); id%8 = b%8 -> each batch's
// 16 blocks on one XCD (T[b]+H[b] = 4 MB ~ per-XCD L2).
// `out` stores are non-temporal: 33.5 MB never re-read; keep LLC for reads.
__global__ __launch_bounds__(256) void gemm2_kernel(
    const unsigned short* __restrict__ Tg,   // [32*512,1024]
    const unsigned short* __restrict__ Hbf,  // [32*512,1024]
    const float* __restrict__ linD, const float* __restrict__ linH,
    float* __restrict__ out) {               // [32,512,512]
  __shared__ __align__(16) unsigned short As[128 * 64];
  __shared__ __align__(16) unsigned short Bs[128 * 64];
  int b = blockIdx.x;
  int t = blockIdx.y;
  int m0 = (t >> 2) * 128, n0 = (t & 3) * 128;
  const unsigned short* A = Tg + (size_t)b * 512 * D_DIM;
  const unsigned short* Bt = Hbf + (size_t)b * 512 * D_DIM;
  int tid = threadIdx.x;
  int lane = tid & 63, wave = tid >> 6;
  int quad = lane >> 4, lrow = lane & 15;
  int wm = wave >> 1, wn = wave & 1;

  floatx4 acc[4][4] = {};
  gemm_core_swz<2, 2, 4, 4, 128>(A, Bt, m0, n0, As, Bs, acc);

  #pragma unroll
  for (int mt = 0; mt < 4; ++mt)
    #pragma unroll
    for (int nt = 0; nt < 4; ++nt) {
      int row = m0 + wm * 64 + mt * 16 + quad * 4;
      int col = n0 + wn * 64 + nt * 16 + lrow;
      float lh = linH[b * 512 + col];
      #pragma unroll
      for (int rr = 0; rr < 4; ++rr) {
        float v = acc[mt][nt][rr] + linD[b * 512 + row + rr] + lh;
        __builtin_nontemporal_store(
            v, &out[((size_t)b * 512 + row + rr) * 512 + col]);
      }
    }
}

extern "C" void kernel_launch(void* const* d_in, const int* in_sizes, int n_in,
                              void* d_out, int out_size, void* d_ws, size_t ws_size,
                              hipStream_t stream) {
  const float* D = (const float*)d_in[0];
  const float* H = (const float*)d_in[1];
  const float* U = (const float*)d_in[2];   // [1025,1024]
  const float* W = (const float*)d_in[3];   // [2049]
  float* out = (float*)d_out;

  char* ws = (char*)d_ws;
  unsigned short* Dbf = (unsigned short*)ws; ws += (size_t)ROWS * D_DIM * 2;   // 32 MB
  unsigned short* Hbf = (unsigned short*)ws; ws += (size_t)ROWS * D_DIM * 2;   // 32 MB
  unsigned short* Tbf = (unsigned short*)ws; ws += (size_t)ROWS * D_DIM * 2;   // 32 MB
  unsigned short* Ut  = (unsigned short*)ws; ws += (size_t)D_DIM * D_DIM * 2;  //  2 MB
  float* linD = (float*)ws;                  ws += (size_t)ROWS * 4;
  float* linH = (float*)ws;                  ws += (size_t)ROWS * 4;

  cast_transU_kernel<<<dim3(2 * ROWS + 1024), 256, 0, stream>>>(
      D, H, U, W, Dbf, Hbf, Ut, linD, linH);
  gemm1_kernel<<<dim3(128, 8), 256, 0, stream>>>(Dbf, Ut, U + (size_t)D_DIM * D_DIM, Tbf);
  gemm2_kernel<<<dim3(32, 16), 256, 0, stream>>>(Tbf, Hbf, linD, linH, out);
}